// Round 10
// baseline (2222.279 us; speedup 1.0000x reference)
//
#include <hip/hip_runtime.h>

// ---------------------------------------------------------------------------
// RatingLayer: 2-round fully-connected 2-node GRU + linear head.
// One [24576,4096]^T bf16 GEMM per round. Round 10: 128x128/BK=64/4-wave GEMM
// with LDS 64KB -> 2 BLOCKS PER CU (two independent barrier domains; block Y
// fills block X's gate stalls). r7 read-ahead quadrant schedule transplanted
// isomorphically (same ledger, same VM6 pools, same swizzle). r9's NT-A and
// lgkm8 reverted (NT-A raised FETCH: A has real cross-block reuse).
// ---------------------------------------------------------------------------

typedef __bf16 bf16x8 __attribute__((ext_vector_type(8)));
typedef float  f32x4  __attribute__((ext_vector_type(4)));
typedef unsigned short u16x4 __attribute__((ext_vector_type(4)));

#define HH    4096
#define NI_D  2048
#define N3H   12288
#define N6H   24576
#define BSZ   4096
#define BM    128
#define BN    128
#define BK    64
#define MT    (BSZ / BM)     // 32
#define NT    (N6H / BN)     // 192
#define GRID_GEMM (MT * NT)  // 6144
#define NKT   (HH / BK)      // 64 K-tiles

#define NB_W  98304
#define NB_C  16384

__device__ __forceinline__ unsigned short f2bf(float f) {
  unsigned u = __float_as_uint(f);
  u += 0x7FFFu + ((u >> 16) & 1u);
  return (unsigned short)(u >> 16);
}
__device__ __forceinline__ float bf2f(unsigned short s) {
  return __uint_as_float(((unsigned)s) << 16);
}

__device__ __forceinline__ void gload16(const void* g, void* l) {
  void* gv = (void*)g;
  __builtin_amdgcn_global_load_lds(
      (__attribute__((address_space(1))) unsigned int*)gv,
      (__attribute__((address_space(3))) unsigned int*)l,
      16, 0, 0);
}

// --- fused prep: Wc[j][k] = bf16(j<3H ? W_ih[j][(k+NI)%H] : W_hh[j-3H][k]);
//     hb = bf16(features)
__global__ void __launch_bounds__(256)
prep(const float* __restrict__ Wih, const float* __restrict__ Whh,
     const float* __restrict__ feat,
     unsigned short* __restrict__ Wc, unsigned short* __restrict__ hb)
{
  int bid = blockIdx.x;
  if (bid < NB_W) {
    int idx = (bid * 256 + threadIdx.x) << 2;
    int j = idx >> 12;
    int k = idx & 4095;
    const float* src;
    if (j < N3H) src = Wih + (size_t)j * HH + ((k + NI_D) & (HH - 1));
    else         src = Whh + (size_t)(j - N3H) * HH + k;
    f32x4 v = *(const f32x4*)src;
    u16x4 o = { f2bf(v[0]), f2bf(v[1]), f2bf(v[2]), f2bf(v[3]) };
    *(u16x4*)(Wc + idx) = o;
  } else {
    int i = ((bid - NB_W) * 256 + threadIdx.x) << 2;
    f32x4 v = *(const f32x4*)(feat + i);
    u16x4 o = { f2bf(v[0]), f2bf(v[1]), f2bf(v[2]), f2bf(v[3]) };
    *(u16x4*)(hb + i) = o;
  }
}

// ---------------------------------------------------------------------------
// GEMM helpers. LDS (64 KB): A buf d at d*16384 (128 rows x 128 B),
// B at 32768 + d*16384. Granule g = 32 rows = one gload16 per thread (4 KB).
// Linear LDS dest; global source column pre-swizzled by ((row&7)<<4).
// A frags 2-3 (ahi) live in granules G1(wm0)/G3(wm1); frags 0-1 (alo) in
// G0/G2. B: wn=0 -> b01=G0, b23=G1; wn=1 -> b01=G2, b23=G3.
// ---------------------------------------------------------------------------
__device__ __forceinline__ void stageA(const char* a_base, char* lds, int ldst,
                                       int d, int kt, int g) {
  int kc = (kt < NKT) ? kt : 0;                 // dummy tail loads, race-safe
  gload16(a_base + (size_t)kc * 128 + (size_t)g * 262144,
          lds + d * 16384 + g * 4096 + ldst);
}
__device__ __forceinline__ void stageB(const char* b_base, char* lds, int ldst,
                                       int d, int kt, int g) {
  int kc = (kt < NKT) ? kt : 0;
  gload16(b_base + (size_t)kc * 128 + (size_t)g * 262144,
          lds + 32768 + d * 16384 + g * 4096 + ldst);
}

// One C-quadrant over full K=64: 8 MFMAs into acc[MB..MB+1][NB..NB+1].
template <int MB, int NB>
__device__ __forceinline__ void mfmaQ(f32x4 (&acc)[4][4],
                                      const bf16x8 (&af)[2][2],
                                      const bf16x8 (&bf)[2][2]) {
  __builtin_amdgcn_s_setprio(1);
#pragma unroll
  for (int ks = 0; ks < 2; ++ks)
#pragma unroll
    for (int mf = 0; mf < 2; ++mf)
#pragma unroll
      for (int nf = 0; nf < 2; ++nf)
        acc[MB + mf][NB + nf] = __builtin_amdgcn_mfma_f32_16x16x32_bf16(
            af[mf][ks], bf[nf][ks], acc[MB + mf][NB + nf], 0, 0, 0);
  __builtin_amdgcn_s_setprio(0);
}

#define BAR   __builtin_amdgcn_s_barrier()
#define SB    __builtin_amdgcn_sched_barrier(0)
#define LGKM0 do { asm volatile("s_waitcnt lgkmcnt(0)" ::: "memory"); SB; } while (0)
#define VM6   asm volatile("s_waitcnt vmcnt(6)" ::: "memory")

// One K-tile, read-ahead schedule (r7 ledger, transplanted). On entry:
// ahiC/b01C hold this tile's fragments (read during previous tile's ph3,
// landed via ph0's LGKM0). ph3 fills ahiN/b01N from buffer D^1.
// Stage ledger per wave (steady state):
//   ph0: A(t1)G0,G2 -> D^1 | ph1: A(t2)G1,G3 -> D | ph2: B(t2)G0,G1 -> D
//   ph3: B(t2)G2,G3 -> D           (8 loads/tile, 2 per phase)
// Gates: ph0 vmcnt(6) retires (t-1)ph1-and-older -> alo(t) staging landed.
//        ph2 vmcnt(6) retires (t-1)ph3-and-older -> D^1 fully valid for ph3
//        reads. Every staged LDS region's readers completed a barrier earlier.
template <int D>
__device__ __forceinline__ void kblock(char* lds, const char* a_base,
                                       const char* b_base, int ldst,
                                       int aro, int bro, int offk0, int offk1,
                                       int t1, int t2, f32x4 (&acc)[4][4],
                                       bf16x8 (&ahiC)[2][2], bf16x8 (&b01C)[2][2],
                                       bf16x8 (&ahiN)[2][2], bf16x8 (&b01N)[2][2]) {
  const char* LA  = lds + D * 16384 + aro;
  const char* LB  = lds + 32768 + D * 16384 + bro;
  const char* LAn = lds + (D ^ 1) * 16384 + aro;
  const char* LBn = lds + 32768 + (D ^ 1) * 16384 + bro;
  bf16x8 alo[2][2], b23[2][2];

  // ---- ph0: MFMA(ahi,b01); read-ahead b23; stage A(t1)G0,G2 -> D^1.
  LGKM0;                                 // ahiC,b01C landed
#pragma unroll
  for (int nf = 0; nf < 2; ++nf) {
    b23[nf][0] = *(const bf16x8*)(LB + (2 + nf) * 2048 + offk0);
    b23[nf][1] = *(const bf16x8*)(LB + (2 + nf) * 2048 + offk1);
  }
  stageA(a_base, lds, ldst, D ^ 1, t1, 0);
  stageA(a_base, lds, ldst, D ^ 1, t1, 2);
  SB;
  mfmaQ<2, 0>(acc, ahiC, b01C);
  VM6;
  BAR;

  // ---- ph1: MFMA(ahi,b23); read-ahead alo; stage A(t2)G1,G3 -> D.
  LGKM0;                                 // b23 landed (flew under ph0 MFMA)
#pragma unroll
  for (int mf = 0; mf < 2; ++mf) {
    alo[mf][0] = *(const bf16x8*)(LA + mf * 2048 + offk0);
    alo[mf][1] = *(const bf16x8*)(LA + mf * 2048 + offk1);
  }
  stageA(a_base, lds, ldst, D, t2, 1);
  stageA(a_base, lds, ldst, D, t2, 3);
  SB;
  mfmaQ<2, 2>(acc, ahiC, b23);
  BAR;

  // ---- ph2: MFMA(alo,b01); stage B(t2)G0,G1 -> D; gate D^1 validity.
  LGKM0;                                 // alo landed
  stageB(b_base, lds, ldst, D, t2, 0);
  stageB(b_base, lds, ldst, D, t2, 1);
  SB;
  mfmaQ<0, 0>(acc, alo, b01C);
  VM6;
  BAR;

  // ---- ph3: MFMA(alo,b23); read-ahead next tile's ahi,b01 from D^1;
  //           stage B(t2)G2,G3 -> D.
#pragma unroll
  for (int mf = 0; mf < 2; ++mf) {
    ahiN[mf][0] = *(const bf16x8*)(LAn + (2 + mf) * 2048 + offk0);
    ahiN[mf][1] = *(const bf16x8*)(LAn + (2 + mf) * 2048 + offk1);
  }
#pragma unroll
  for (int nf = 0; nf < 2; ++nf) {
    b01N[nf][0] = *(const bf16x8*)(LBn + nf * 2048 + offk0);
    b01N[nf][1] = *(const bf16x8*)(LBn + nf * 2048 + offk1);
  }
  stageB(b_base, lds, ldst, D, t2, 2);
  stageB(b_base, lds, ldst, D, t2, 3);
  SB;
  mfmaQ<0, 2>(acc, alo, b23);
  BAR;
}

// ---------------------------------------------------------------------------
// C[4096, 24576] bf16 = A[4096,4096] * B[24576,4096]^T   (bf16 in, bf16 out)
// 128x128 tile, BK=64, 256 threads (4 waves, 2Mx2N), LDS 64 KB -> 2 blocks/CU.
// ---------------------------------------------------------------------------
__global__ void __launch_bounds__(256, 2)
gemm_bt(const unsigned short* __restrict__ A,
        const unsigned short* __restrict__ B,
        unsigned short* __restrict__ C)
{
  __shared__ alignas(16) char lds[65536];

  int bid = blockIdx.x;
  int wg  = (bid & 7) * (GRID_GEMM / 8) + (bid >> 3);  // XCD swizzle, 6144%8==0
  int nt  = wg / MT;          // n-major: 32 consecutive wg share one W panel
  int mt  = wg % MT;
  int m0  = mt * BM;
  int n0  = nt * BN;

  int t  = threadIdx.x;
  int wv = t >> 6;            // 0..3
  int l  = t & 63;
  int wm = wv >> 1;           // 0..1: 64 rows of C
  int wn = wv & 1;            // 0..1: 64 cols of C

  // staging: thread covers row rloc of a 32-row granule, 16B chunk (l&7),
  // source column XOR-preswizzled by row&7 = l>>3.
  int rloc   = wv * 8 + (l >> 3);
  int sg_col = ((l & 7) ^ (l >> 3)) << 4;
  const char* a_base = (const char*)A + (size_t)(m0 + rloc) * 8192 + sg_col;
  const char* b_base = (const char*)B + (size_t)(n0 + rloc) * 8192 + sg_col;
  int ldst = wv * 1024;       // wave-uniform LDS dest offset within granule

  // read-side swizzled offsets
  int offk0 = ((l >> 4) << 4) ^ ((l & 7) << 4);
  int offk1 = offk0 ^ 64;
  int aro = (wm * 64 + (l & 15)) * 128;
  int bro = (wn * 64 + (l & 15)) * 128;

  f32x4 acc[4][4] = {};
  bf16x8 ahiA[2][2], b01A[2][2], ahiB[2][2], b01B[2][2];

  // prologue: D0 complete (8 loads), then steady-state in-flight set
  // {A(1)G1,G3, B(1)G0-3} (6 loads). vmcnt(6) -> D0 landed. Then read
  // tile0's entry fragments (ahiA,b01A) from D0; ph0's LGKM0 gates them.
#pragma unroll
  for (int g = 0; g < 4; ++g) stageA(a_base, lds, ldst, 0, 0, g);
#pragma unroll
  for (int g = 0; g < 4; ++g) stageB(b_base, lds, ldst, 0, 0, g);
  stageA(a_base, lds, ldst, 1, 1, 1);
  stageA(a_base, lds, ldst, 1, 1, 3);
#pragma unroll
  for (int g = 0; g < 4; ++g) stageB(b_base, lds, ldst, 1, 1, g);
  asm volatile("s_waitcnt vmcnt(6)" ::: "memory");
  BAR;
  {
    const char* LA0 = lds + aro;
    const char* LB0 = lds + 32768 + bro;
#pragma unroll
    for (int mf = 0; mf < 2; ++mf) {
      ahiA[mf][0] = *(const bf16x8*)(LA0 + (2 + mf) * 2048 + offk0);
      ahiA[mf][1] = *(const bf16x8*)(LA0 + (2 + mf) * 2048 + offk1);
    }
#pragma unroll
    for (int nf = 0; nf < 2; ++nf) {
      b01A[nf][0] = *(const bf16x8*)(LB0 + nf * 2048 + offk0);
      b01A[nf][1] = *(const bf16x8*)(LB0 + nf * 2048 + offk1);
    }
  }

#pragma unroll 1
  for (int tt = 0; tt < NKT; tt += 2) {
    kblock<0>(lds, a_base, b_base, ldst, aro, bro, offk0, offk1,
              tt + 1, tt + 2, acc, ahiA, b01A, ahiB, b01B);
    kblock<1>(lds, a_base, b_base, ldst, aro, bro, offk0, offk1,
              tt + 2, tt + 3, acc, ahiB, b01B, ahiA, b01A);
  }
  asm volatile("s_waitcnt vmcnt(0) lgkmcnt(0)" ::: "memory");  // drain tails

  // C-write: frag layout col = lane&15, row = (lane>>4)*4 + reg (m89)
  int crow = m0 + wm * 64 + ((l >> 4) << 2);
  int ccol = n0 + wn * 64 + (l & 15);
#pragma unroll
  for (int mf = 0; mf < 4; ++mf)
#pragma unroll
    for (int nf = 0; nf < 4; ++nf)
#pragma unroll
      for (int i = 0; i < 4; ++i)
        C[(size_t)(crow + mf * 16 + i) * N6H + (ccol + nf * 16)] =
            f2bf(acc[mf][nf][i]);
}

// --- round-1 GRU: h_old = features (f32); writes h1 as bf16 only.
__global__ void __launch_bounds__(256)
gru1(const unsigned short* __restrict__ C, const float* __restrict__ h_old,
     const float* __restrict__ b_ih, const float* __restrict__ b_hh,
     unsigned short* __restrict__ h_bf)
{
  int idx = blockIdx.x * 256 + threadIdx.x;
  int b = idx >> 10;
  int j = (idx & 1023) << 2;
  const unsigned short* Cr = C + (size_t)b * N6H;
  u16x4 gir = *(const u16x4*)(Cr + j);
  u16x4 giz = *(const u16x4*)(Cr + HH + j);
  u16x4 gin = *(const u16x4*)(Cr + 2 * HH + j);
  u16x4 ghr = *(const u16x4*)(Cr + 3 * HH + j);
  u16x4 ghz = *(const u16x4*)(Cr + 4 * HH + j);
  u16x4 ghn = *(const u16x4*)(Cr + 5 * HH + j);
  f32x4 bir = *(const f32x4*)(b_ih + j);
  f32x4 biz = *(const f32x4*)(b_ih + HH + j);
  f32x4 bin = *(const f32x4*)(b_ih + 2 * HH + j);
  f32x4 bhr = *(const f32x4*)(b_hh + j);
  f32x4 bhz = *(const f32x4*)(b_hh + HH + j);
  f32x4 bhn = *(const f32x4*)(b_hh + 2 * HH + j);
  f32x4 ho  = *(const f32x4*)(h_old + (size_t)b * HH + j);
  u16x4 hb;
#pragma unroll
  for (int e = 0; e < 4; ++e) {
    float r = 1.f / (1.f + expf(-(bf2f(gir[e]) + bir[e] + bf2f(ghr[e]) + bhr[e])));
    float z = 1.f / (1.f + expf(-(bf2f(giz[e]) + biz[e] + bf2f(ghz[e]) + bhz[e])));
    float n = tanhf(bf2f(gin[e]) + bin[e] + r * (bf2f(ghn[e]) + bhn[e]));
    hb[e] = f2bf((1.f - z) * n + z * ho[e]);
  }
  *(u16x4*)(h_bf + (size_t)b * HH + j) = hb;
}

// --- round-2 GRU fused with FC head: h_old = h1 (bf16); per-block partial
// dot(h2, fc_w) -> atomicAdd(out[b]). out zeroed by memset each call.
__global__ void __launch_bounds__(256)
gru2_fc(const unsigned short* __restrict__ C,
        const unsigned short* __restrict__ h_old_bf,
        const float* __restrict__ b_ih, const float* __restrict__ b_hh,
        const float* __restrict__ fcw, const float* __restrict__ fcb,
        float* __restrict__ out)
{
  int idx = blockIdx.x * 256 + threadIdx.x;
  int b = idx >> 10;
  int j = (idx & 1023) << 2;
  const unsigned short* Cr = C + (size_t)b * N6H;
  u16x4 gir = *(const u16x4*)(Cr + j);
  u16x4 giz = *(const u16x4*)(Cr + HH + j);
  u16x4 gin = *(const u16x4*)(Cr + 2 * HH + j);
  u16x4 ghr = *(const u16x4*)(Cr + 3 * HH + j);
  u16x4 ghz = *(const u16x4*)(Cr + 4 * HH + j);
  u16x4 ghn = *(const u16x4*)(Cr + 5 * HH + j);
  f32x4 bir = *(const f32x4*)(b_ih + j);
  f32x4 biz = *(const f32x4*)(b_ih + HH + j);
  f32x4 bin = *(const f32x4*)(b_ih + 2 * HH + j);
  f32x4 bhr = *(const f32x4*)(b_hh + j);
  f32x4 bhz = *(const f32x4*)(b_hh + HH + j);
  f32x4 bhn = *(const f32x4*)(b_hh + 2 * HH + j);
  u16x4 hob = *(const u16x4*)(h_old_bf + (size_t)b * HH + j);
  f32x4 fw  = *(const f32x4*)(fcw + j);
  float s = 0.f;
#pragma unroll
  for (int e = 0; e < 4; ++e) {
    float r = 1.f / (1.f + expf(-(bf2f(gir[e]) + bir[e] + bf2f(ghr[e]) + bhr[e])));
    float z = 1.f / (1.f + expf(-(bf2f(giz[e]) + biz[e] + bf2f(ghz[e]) + bhz[e])));
    float n = tanhf(bf2f(gin[e]) + bin[e] + r * (bf2f(ghn[e]) + bhn[e]));
    float h = (1.f - z) * n + z * bf2f(hob[e]);
    s += h * fw[e];
  }
#pragma unroll
  for (int off = 32; off > 0; off >>= 1) s += __shfl_down(s, off);
  __shared__ float red[4];
  if ((threadIdx.x & 63) == 0) red[threadIdx.x >> 6] = s;
  __syncthreads();
  if (threadIdx.x == 0) {
    float v = red[0] + red[1] + red[2] + red[3];
    if ((blockIdx.x & 3) == 0) v += fcb[0];
    atomicAdd(&out[b], v);
  }
}

extern "C" void kernel_launch(void* const* d_in, const int* in_sizes, int n_in,
                              void* d_out, int out_size, void* d_ws, size_t ws_size,
                              hipStream_t stream)
{
  const float* feat = (const float*)d_in[0];
  const float* Wih  = (const float*)d_in[1];
  const float* bih  = (const float*)d_in[2];
  const float* Whh  = (const float*)d_in[3];
  const float* bhh  = (const float*)d_in[4];
  const float* fcw  = (const float*)d_in[5];
  const float* fcb  = (const float*)d_in[6];
  float* out = (float*)d_out;

  char* ws = (char*)d_ws;
  unsigned short* Wc   = (unsigned short*)ws;                    // 201326592 B
  unsigned short* Cbuf = (unsigned short*)(ws + 201326592);      // 201326592 B
  unsigned short* hb   = (unsigned short*)(ws + 402653184);      //  33554432 B
  // total: 436207616 B

  hipMemsetAsync(out, 0, (size_t)out_size * sizeof(float), stream);
  prep<<<NB_W + NB_C, 256, 0, stream>>>(Wih, Whh, feat, Wc, hb);

  gemm_bt<<<GRID_GEMM, 256, 0, stream>>>(hb, Wc, Cbuf);
  gru1<<<16384, 256, 0, stream>>>(Cbuf, feat, bih, bhh, hb);

  gemm_bt<<<GRID_GEMM, 256, 0, stream>>>(hb, Wc, Cbuf);
  gru2_fc<<<16384, 256, 0, stream>>>(Cbuf, hb, bih, bhh, fcw, fcb, out);
}

// Round 11
// 1996.898 us; speedup vs baseline: 1.1129x; 1.1129x over previous
//
#include <hip/hip_runtime.h>

// ---------------------------------------------------------------------------
// RatingLayer: 2-round fully-connected 2-node GRU + linear head.
// One [24576,4096]^T bf16 GEMM per round. Round 11 = round 7 (best) + 3-DEEP
// B BUFFERING (LDS 160 KB: A 2x32K, B 3x32K). B(=W) streams from HBM
// (FETCH 920MB, ~900cy); 2-deep gave its gates only 3-4 phases (~470-620cy)
// of flight. 3-deep B -> B flights 5-6 phases (~780-930cy) >= HBM latency.
// Gates re-derived: vmcnt(8)@ph0-end, vmcnt(10)@ph2-end. r10's 128^2 tiles
// reverted (FETCH 3.2GB, memory-bound).
// ---------------------------------------------------------------------------

typedef __bf16 bf16x8 __attribute__((ext_vector_type(8)));
typedef float  f32x4  __attribute__((ext_vector_type(4)));
typedef unsigned short u16x4 __attribute__((ext_vector_type(4)));

#define HH    4096
#define NI_D  2048
#define N3H   12288
#define N6H   24576
#define BSZ   4096
#define BM    256
#define BN    256
#define BK    64
#define MT    (BSZ / BM)     // 16
#define NT    (N6H / BN)     // 96
#define GRID_GEMM (MT * NT)  // 1536
#define NKT   (HH / BK)      // 64 K-tiles

#define NB_W  98304
#define NB_C  16384

__device__ __forceinline__ unsigned short f2bf(float f) {
  unsigned u = __float_as_uint(f);
  u += 0x7FFFu + ((u >> 16) & 1u);
  return (unsigned short)(u >> 16);
}
__device__ __forceinline__ float bf2f(unsigned short s) {
  return __uint_as_float(((unsigned)s) << 16);
}

__device__ __forceinline__ void gload16(const void* g, void* l) {
  void* gv = (void*)g;
  __builtin_amdgcn_global_load_lds(
      (__attribute__((address_space(1))) unsigned int*)gv,
      (__attribute__((address_space(3))) unsigned int*)l,
      16, 0, 0);
}

// --- fused prep: Wc[j][k] = bf16(j<3H ? W_ih[j][(k+NI)%H] : W_hh[j-3H][k]);
//     hb = bf16(features)
__global__ void __launch_bounds__(256)
prep(const float* __restrict__ Wih, const float* __restrict__ Whh,
     const float* __restrict__ feat,
     unsigned short* __restrict__ Wc, unsigned short* __restrict__ hb)
{
  int bid = blockIdx.x;
  if (bid < NB_W) {
    int idx = (bid * 256 + threadIdx.x) << 2;
    int j = idx >> 12;
    int k = idx & 4095;
    const float* src;
    if (j < N3H) src = Wih + (size_t)j * HH + ((k + NI_D) & (HH - 1));
    else         src = Whh + (size_t)(j - N3H) * HH + k;
    f32x4 v = *(const f32x4*)src;
    u16x4 o = { f2bf(v[0]), f2bf(v[1]), f2bf(v[2]), f2bf(v[3]) };
    *(u16x4*)(Wc + idx) = o;
  } else {
    int i = ((bid - NB_W) * 256 + threadIdx.x) << 2;
    f32x4 v = *(const f32x4*)(feat + i);
    u16x4 o = { f2bf(v[0]), f2bf(v[1]), f2bf(v[2]), f2bf(v[3]) };
    *(u16x4*)(hb + i) = o;
  }
}

// ---------------------------------------------------------------------------
// GEMM helpers. LDS (160 KB): A buf d (d=0,1) at d*32768 (256 rows x 128 B);
// B buf q (q=0,1,2) at 65536 + q*32768. Granule g = 64 rows = one gload16
// per thread (8 KB). Linear LDS dest; global source column pre-swizzled by
// ((row&7)<<4) (rule 21 both-sides).
// A frags 4-7 (a47) live in granules G1(wm0)/G3(wm1); frags 0-3 (a03) G0/G2.
// ---------------------------------------------------------------------------
__device__ __forceinline__ void stageA(const char* a_base, char* lds, int ldst,
                                       int d, int kt, int g) {
  int kc = (kt < NKT) ? kt : 0;                 // dummy tail loads, race-safe
  gload16(a_base + (size_t)kc * 128 + (size_t)g * 524288,
          lds + d * 32768 + g * 8192 + ldst);
}
__device__ __forceinline__ void stageB(const char* b_base, char* lds, int ldst,
                                       int q, int kt, int g) {
  int kc = (kt < NKT) ? kt : 0;
  gload16(b_base + (size_t)kc * 128 + (size_t)g * 524288,
          lds + 65536 + q * 32768 + g * 8192 + ldst);
}

// One C-quadrant over full K=64: 16 MFMAs into acc[MB..MB+3][NB..NB+1].
template <int MB, int NB>
__device__ __forceinline__ void mfmaQ(f32x4 (&acc)[8][4],
                                      const bf16x8 (&af)[4][2],
                                      const bf16x8 (&bf)[2][2]) {
  __builtin_amdgcn_s_setprio(1);
#pragma unroll
  for (int ks = 0; ks < 2; ++ks)
#pragma unroll
    for (int mf = 0; mf < 4; ++mf)
#pragma unroll
      for (int nf = 0; nf < 2; ++nf)
        acc[MB + mf][NB + nf] = __builtin_amdgcn_mfma_f32_16x16x32_bf16(
            af[mf][ks], bf[nf][ks], acc[MB + mf][NB + nf], 0, 0, 0);
  __builtin_amdgcn_s_setprio(0);
}

#define BAR   __builtin_amdgcn_s_barrier()
#define SB    __builtin_amdgcn_sched_barrier(0)
#define LGKM0 do { asm volatile("s_waitcnt lgkmcnt(0)" ::: "memory"); SB; } while (0)
#define VM8   asm volatile("s_waitcnt vmcnt(8)" ::: "memory")
#define VM10  asm volatile("s_waitcnt vmcnt(10)" ::: "memory")

// One K-tile, read-ahead schedule with 3-deep B. On entry: a47c/b01c hold
// this tile's fragments (read during previous tile's ph3, landed via ph0's
// LGKM0). ph3 fills a47n/b01n for the next tile (A buf AD^1, B buf BD1).
// Stage ledger per wave (steady state, tile t; AD=t&1, BD=t%3, BD1=(t+1)%3):
//   ph0: A(t+1)G0,G2 -> Abuf AD^1   [Abuf AD^1 held A(t-1); read t-1 ph1]
//   ph1: A(t+2)G1,G3 -> Abuf AD     [G1,G3 = a47(t), read t-1 ph3]
//   ph2: B(t+3)G0,G1 -> Bbuf BD     [b01(t) read t-1 ph3]
//   ph3: B(t+3)G2,G3 -> Bbuf BD     [b23(t) read t ph0]
// Gates (issue-order ledger, 12 outstanding at tile entry):
//   ph0-end vmcnt(8): retires B(t+1)x4 [flight 5-6 ph] + A(t)G0,G2 [4 ph]
//     -> ph1's a03 reads and ph3's b01n reads safe.
//   ph2-end vmcnt(10): retires A(t+1)G1,G3 [5 ph] -> ph3's a47n reads safe.
// Never vmcnt(0) in the loop.
template <int AD, int BD, int BD1>
__device__ __forceinline__ void kblock(char* lds, const char* a_base,
                                       const char* b_base, int ldst,
                                       int aro, int bro, int offk0, int offk1,
                                       int tA1, int tA2, int tB3,
                                       f32x4 (&acc)[8][4],
                                       bf16x8 (&a47c)[4][2], bf16x8 (&b01c)[2][2],
                                       bf16x8 (&a47n)[4][2], bf16x8 (&b01n)[2][2]) {
  const char* LA  = lds + AD * 32768 + aro;
  const char* LB  = lds + 65536 + BD * 32768 + bro;
  const char* LAn = lds + (AD ^ 1) * 32768 + aro;
  const char* LBn = lds + 65536 + BD1 * 32768 + bro;
  bf16x8 a03[4][2], b23[2][2];

  // ---- ph0: MFMA(a47,b01); read-ahead b23; stage A(t+1)G0,G2.
  LGKM0;                                 // a47c,b01c landed
#pragma unroll
  for (int nf = 0; nf < 2; ++nf) {
    b23[nf][0] = *(const bf16x8*)(LB + (2 + nf) * 2048 + offk0);
    b23[nf][1] = *(const bf16x8*)(LB + (2 + nf) * 2048 + offk1);
  }
  stageA(a_base, lds, ldst, AD ^ 1, tA1, 0);
  stageA(a_base, lds, ldst, AD ^ 1, tA1, 2);
  SB;
  mfmaQ<4, 0>(acc, a47c, b01c);
  VM8;
  BAR;

  // ---- ph1: MFMA(a47,b23); read-ahead a03; stage A(t+2)G1,G3.
  LGKM0;                                 // b23 landed (flew under ph0 MFMA)
#pragma unroll
  for (int mf = 0; mf < 4; ++mf) {
    a03[mf][0] = *(const bf16x8*)(LA + mf * 2048 + offk0);
    a03[mf][1] = *(const bf16x8*)(LA + mf * 2048 + offk1);
  }
  stageA(a_base, lds, ldst, AD, tA2, 1);
  stageA(a_base, lds, ldst, AD, tA2, 3);
  SB;
  mfmaQ<4, 2>(acc, a47c, b23);
  BAR;

  // ---- ph2: MFMA(a03,b01); stage B(t+3)G0,G1; gate a47n source.
  LGKM0;                                 // a03 landed
  stageB(b_base, lds, ldst, BD, tB3, 0);
  stageB(b_base, lds, ldst, BD, tB3, 1);
  SB;
  mfmaQ<0, 0>(acc, a03, b01c);
  VM10;
  BAR;

  // ---- ph3: MFMA(a03,b23); read-ahead next tile's a47,b01; stage B(t+3)G2,G3.
#pragma unroll
  for (int mf = 0; mf < 4; ++mf) {
    a47n[mf][0] = *(const bf16x8*)(LAn + (4 + mf) * 2048 + offk0);
    a47n[mf][1] = *(const bf16x8*)(LAn + (4 + mf) * 2048 + offk1);
  }
#pragma unroll
  for (int nf = 0; nf < 2; ++nf) {
    b01n[nf][0] = *(const bf16x8*)(LBn + nf * 2048 + offk0);
    b01n[nf][1] = *(const bf16x8*)(LBn + nf * 2048 + offk1);
  }
  stageB(b_base, lds, ldst, BD, tB3, 2);
  stageB(b_base, lds, ldst, BD, tB3, 3);
  SB;
  mfmaQ<0, 2>(acc, a03, b23);
  BAR;
}

// ---------------------------------------------------------------------------
// C[4096, 24576] bf16 = A[4096,4096] * B[24576,4096]^T   (bf16 in, bf16 out)
// 256x256 tile, BK=64, 512 threads (8 waves, 2Mx4N), LDS 160 KB (A x2, B x3).
// ---------------------------------------------------------------------------
__global__ void __launch_bounds__(512, 2)
gemm_bt(const unsigned short* __restrict__ A,
        const unsigned short* __restrict__ B,
        unsigned short* __restrict__ C)
{
  __shared__ alignas(16) char lds[163840];

  int bid = blockIdx.x;
  int wg  = (bid & 7) * (GRID_GEMM / 8) + (bid >> 3);  // XCD swizzle, 1536%8==0
  int nt  = wg / MT;          // n-major: 16 consecutive wg share one W panel
  int mt  = wg % MT;
  int m0  = mt * BM;
  int n0  = nt * BN;

  int t  = threadIdx.x;
  int wv = t >> 6;
  int l  = t & 63;
  int wm = wv >> 2;
  int wn = wv & 3;

  // staging: thread covers row rloc of a 64-row granule, 16B chunk (l&7),
  // source column XOR-preswizzled by row&7 = l>>3.
  int rloc   = wv * 8 + (l >> 3);
  int sg_col = ((l & 7) ^ (l >> 3)) << 4;
  const char* a_base = (const char*)A + (size_t)(m0 + rloc) * 8192 + sg_col;
  const char* b_base = (const char*)B + (size_t)(n0 + rloc) * 8192 + sg_col;
  int ldst = wv * 1024;       // wave-uniform LDS dest offset within granule

  // read-side swizzled offsets
  int offk0 = ((l >> 4) << 4) ^ ((l & 7) << 4);
  int offk1 = offk0 ^ 64;
  int aro = (wm * 128 + (l & 15)) * 128;
  int bro = (wn * 64  + (l & 15)) * 128;

  f32x4 acc[8][4] = {};
  bf16x8 a47A[4][2], b01A[2][2], a47B[4][2], b01B[2][2];

  // prologue (issue order mirrors the steady stream):
  //   must-land set: B(0)G0-3, A(0)G1,G3           (6 issues)
  //   in-flight set: B(1)G0-3, A(0)G0,G2, A(1)G1,G3, B(2)G0-3 (12 issues)
  // vmcnt(12) retires the first 6; entry frags a47(0), b01(0) then readable.
#pragma unroll
  for (int g = 0; g < 4; ++g) stageB(b_base, lds, ldst, 0, 0, g);
  stageA(a_base, lds, ldst, 0, 0, 1);
  stageA(a_base, lds, ldst, 0, 0, 3);
#pragma unroll
  for (int g = 0; g < 4; ++g) stageB(b_base, lds, ldst, 1, 1, g);
  stageA(a_base, lds, ldst, 0, 0, 0);
  stageA(a_base, lds, ldst, 0, 0, 2);
  stageA(a_base, lds, ldst, 1, 1, 1);
  stageA(a_base, lds, ldst, 1, 1, 3);
#pragma unroll
  for (int g = 0; g < 4; ++g) stageB(b_base, lds, ldst, 2, 2, g);
  asm volatile("s_waitcnt vmcnt(12)" ::: "memory");
  BAR;
  {
    const char* LA0 = lds + aro;
    const char* LB0 = lds + 65536 + bro;
#pragma unroll
    for (int mf = 0; mf < 4; ++mf) {
      a47A[mf][0] = *(const bf16x8*)(LA0 + (4 + mf) * 2048 + offk0);
      a47A[mf][1] = *(const bf16x8*)(LA0 + (4 + mf) * 2048 + offk1);
    }
#pragma unroll
    for (int nf = 0; nf < 2; ++nf) {
      b01A[nf][0] = *(const bf16x8*)(LB0 + nf * 2048 + offk0);
      b01A[nf][1] = *(const bf16x8*)(LB0 + nf * 2048 + offk1);
    }
  }

  // main loop: 60 tiles in 10 x 6 (period lcm(2,3)=6), then 4-tile tail.
  // tile t: kblock<t&1, t%3, (t+1)%3>, stage args (t+1, t+2, t+3);
  // entry-reg sets alternate with tile parity.
#pragma unroll 1
  for (int tt = 0; tt < 60; tt += 6) {
    kblock<0, 0, 1>(lds, a_base, b_base, ldst, aro, bro, offk0, offk1,
                    tt + 1, tt + 2, tt + 3, acc, a47A, b01A, a47B, b01B);
    kblock<1, 1, 2>(lds, a_base, b_base, ldst, aro, bro, offk0, offk1,
                    tt + 2, tt + 3, tt + 4, acc, a47B, b01B, a47A, b01A);
    kblock<0, 2, 0>(lds, a_base, b_base, ldst, aro, bro, offk0, offk1,
                    tt + 3, tt + 4, tt + 5, acc, a47A, b01A, a47B, b01B);
    kblock<1, 0, 1>(lds, a_base, b_base, ldst, aro, bro, offk0, offk1,
                    tt + 4, tt + 5, tt + 6, acc, a47B, b01B, a47A, b01A);
    kblock<0, 1, 2>(lds, a_base, b_base, ldst, aro, bro, offk0, offk1,
                    tt + 5, tt + 6, tt + 7, acc, a47A, b01A, a47B, b01B);
    kblock<1, 2, 0>(lds, a_base, b_base, ldst, aro, bro, offk0, offk1,
                    tt + 6, tt + 7, tt + 8, acc, a47B, b01B, a47A, b01A);
  }
  // tail: tiles 60..63 (stage args beyond NKT become dummy kc=0 loads,
  // landing only in buffers whose readers already finished — race-safe).
  kblock<0, 0, 1>(lds, a_base, b_base, ldst, aro, bro, offk0, offk1,
                  61, 62, 63, acc, a47A, b01A, a47B, b01B);
  kblock<1, 1, 2>(lds, a_base, b_base, ldst, aro, bro, offk0, offk1,
                  62, 63, 64, acc, a47B, b01B, a47A, b01A);
  kblock<0, 2, 0>(lds, a_base, b_base, ldst, aro, bro, offk0, offk1,
                  63, 64, 65, acc, a47A, b01A, a47B, b01B);
  kblock<1, 0, 1>(lds, a_base, b_base, ldst, aro, bro, offk0, offk1,
                  64, 65, 66, acc, a47B, b01B, a47A, b01A);
  asm volatile("s_waitcnt vmcnt(0) lgkmcnt(0)" ::: "memory");  // drain tails

  // C-write: frag layout col = lane&15, row = (lane>>4)*4 + reg (m89)
  int crow = m0 + wm * 128 + ((l >> 4) << 2);
  int ccol = n0 + wn * 64 + (l & 15);
#pragma unroll
  for (int mf = 0; mf < 8; ++mf)
#pragma unroll
    for (int nf = 0; nf < 4; ++nf)
#pragma unroll
      for (int i = 0; i < 4; ++i)
        C[(size_t)(crow + mf * 16 + i) * N6H + (ccol + nf * 16)] =
            f2bf(acc[mf][nf][i]);
}

// --- round-1 GRU: h_old = features (f32); writes h1 as bf16 only.
__global__ void __launch_bounds__(256)
gru1(const unsigned short* __restrict__ C, const float* __restrict__ h_old,
     const float* __restrict__ b_ih, const float* __restrict__ b_hh,
     unsigned short* __restrict__ h_bf)
{
  int idx = blockIdx.x * 256 + threadIdx.x;
  int b = idx >> 10;
  int j = (idx & 1023) << 2;
  const unsigned short* Cr = C + (size_t)b * N6H;
  u16x4 gir = *(const u16x4*)(Cr + j);
  u16x4 giz = *(const u16x4*)(Cr + HH + j);
  u16x4 gin = *(const u16x4*)(Cr + 2 * HH + j);
  u16x4 ghr = *(const u16x4*)(Cr + 3 * HH + j);
  u16x4 ghz = *(const u16x4*)(Cr + 4 * HH + j);
  u16x4 ghn = *(const u16x4*)(Cr + 5 * HH + j);
  f32x4 bir = *(const f32x4*)(b_ih + j);
  f32x4 biz = *(const f32x4*)(b_ih + HH + j);
  f32x4 bin = *(const f32x4*)(b_ih + 2 * HH + j);
  f32x4 bhr = *(const f32x4*)(b_hh + j);
  f32x4 bhz = *(const f32x4*)(b_hh + HH + j);
  f32x4 bhn = *(const f32x4*)(b_hh + 2 * HH + j);
  f32x4 ho  = *(const f32x4*)(h_old + (size_t)b * HH + j);
  u16x4 hb;
#pragma unroll
  for (int e = 0; e < 4; ++e) {
    float r = 1.f / (1.f + expf(-(bf2f(gir[e]) + bir[e] + bf2f(ghr[e]) + bhr[e])));
    float z = 1.f / (1.f + expf(-(bf2f(giz[e]) + biz[e] + bf2f(ghz[e]) + bhz[e])));
    float n = tanhf(bf2f(gin[e]) + bin[e] + r * (bf2f(ghn[e]) + bhn[e]));
    hb[e] = f2bf((1.f - z) * n + z * ho[e]);
  }
  *(u16x4*)(h_bf + (size_t)b * HH + j) = hb;
}

// --- round-2 GRU fused with FC head: h_old = h1 (bf16); per-block partial
// dot(h2, fc_w) -> atomicAdd(out[b]). out zeroed by memset each call.
__global__ void __launch_bounds__(256)
gru2_fc(const unsigned short* __restrict__ C,
        const unsigned short* __restrict__ h_old_bf,
        const float* __restrict__ b_ih, const float* __restrict__ b_hh,
        const float* __restrict__ fcw, const float* __restrict__ fcb,
        float* __restrict__ out)
{
  int idx = blockIdx.x * 256 + threadIdx.x;
  int b = idx >> 10;
  int j = (idx & 1023) << 2;
  const unsigned short* Cr = C + (size_t)b * N6H;
  u16x4 gir = *(const u16x4*)(Cr + j);
  u16x4 giz = *(const u16x4*)(Cr + HH + j);
  u16x4 gin = *(const u16x4*)(Cr + 2 * HH + j);
  u16x4 ghr = *(const u16x4*)(Cr + 3 * HH + j);
  u16x4 ghz = *(const u16x4*)(Cr + 4 * HH + j);
  u16x4 ghn = *(const u16x4*)(Cr + 5 * HH + j);
  f32x4 bir = *(const f32x4*)(b_ih + j);
  f32x4 biz = *(const f32x4*)(b_ih + HH + j);
  f32x4 bin = *(const f32x4*)(b_ih + 2 * HH + j);
  f32x4 bhr = *(const f32x4*)(b_hh + j);
  f32x4 bhz = *(const f32x4*)(b_hh + HH + j);
  f32x4 bhn = *(const f32x4*)(b_hh + 2 * HH + j);
  u16x4 hob = *(const u16x4*)(h_old_bf + (size_t)b * HH + j);
  f32x4 fw  = *(const f32x4*)(fcw + j);
  float s = 0.f;
#pragma unroll
  for (int e = 0; e < 4; ++e) {
    float r = 1.f / (1.f + expf(-(bf2f(gir[e]) + bir[e] + bf2f(ghr[e]) + bhr[e])));
    float z = 1.f / (1.f + expf(-(bf2f(giz[e]) + biz[e] + bf2f(ghz[e]) + bhz[e])));
    float n = tanhf(bf2f(gin[e]) + bin[e] + r * (bf2f(ghn[e]) + bhn[e]));
    float h = (1.f - z) * n + z * bf2f(hob[e]);
    s += h * fw[e];
  }
#pragma unroll
  for (int off = 32; off > 0; off >>= 1) s += __shfl_down(s, off);
  __shared__ float red[4];
  if ((threadIdx.x & 63) == 0) red[threadIdx.x >> 6] = s;
  __syncthreads();
  if (threadIdx.x == 0) {
    float v = red[0] + red[1] + red[2] + red[3];
    if ((blockIdx.x & 3) == 0) v += fcb[0];
    atomicAdd(&out[b], v);
  }
}

extern "C" void kernel_launch(void* const* d_in, const int* in_sizes, int n_in,
                              void* d_out, int out_size, void* d_ws, size_t ws_size,
                              hipStream_t stream)
{
  const float* feat = (const float*)d_in[0];
  const float* Wih  = (const float*)d_in[1];
  const float* bih  = (const float*)d_in[2];
  const float* Whh  = (const float*)d_in[3];
  const float* bhh  = (const float*)d_in[4];
  const float* fcw  = (const float*)d_in[5];
  const float* fcb  = (const float*)d_in[6];
  float* out = (float*)d_out;

  char* ws = (char*)d_ws;
  unsigned short* Wc   = (unsigned short*)ws;                    // 201326592 B
  unsigned short* Cbuf = (unsigned short*)(ws + 201326592);      // 201326592 B
  unsigned short* hb   = (unsigned short*)(ws + 402653184);      //  33554432 B
  // total: 436207616 B

  hipMemsetAsync(out, 0, (size_t)out_size * sizeof(float), stream);
  prep<<<NB_W + NB_C, 256, 0, stream>>>(Wih, Whh, feat, Wc, hb);

  gemm_bt<<<GRID_GEMM, 512, 0, stream>>>(hb, Wc, Cbuf);
  gru1<<<16384, 256, 0, stream>>>(Cbuf, feat, bih, bhh, hb);

  gemm_bt<<<GRID_GEMM, 512, 0, stream>>>(hb, Wc, Cbuf);
  gru2_fc<<<16384, 256, 0, stream>>>(Cbuf, hb, bih, bhh, fcw, fcb, out);
}

// Round 12
// 1576.593 us; speedup vs baseline: 1.4095x; 1.2666x over previous
//
#include <hip/hip_runtime.h>

// ---------------------------------------------------------------------------
// RatingLayer: 2-round fully-connected 2-node GRU + linear head.
// Round 12: GRU + FC FUSED INTO THE GEMM EPILOGUE. W rows gate-interleaved
// (Wc row r = j*6+g) so a BN=192 block owns 32 complete outputs; epilogue
// stages acc->LDS (C never touches HBM), computes GRU in-block, writes h1
// (round 1) or FC partial atomics (round 2). GEMM core = r7 read-ahead
// schedule re-laddered for 3 B-granules (7 loads/tile, gates VM6@ph0/ph2).
// r11's 3-deep B reverted (I-cache blowup + L2 pressure, 37% util).
// ---------------------------------------------------------------------------

typedef __bf16 bf16x8 __attribute__((ext_vector_type(8)));
typedef float  f32x4  __attribute__((ext_vector_type(4)));
typedef unsigned short u16x4 __attribute__((ext_vector_type(4)));
typedef unsigned short u16x8 __attribute__((ext_vector_type(8)));

#define HH    4096
#define NI_D  2048
#define N3H   12288
#define N6H   24576
#define BSZ   4096
#define BM    256
#define BN    192        // 32 outputs x 6 gates
#define BK    64
#define MT    (BSZ / BM)     // 16
#define NTN   (N6H / BN)     // 128
#define GRID_GEMM (MT * NTN) // 2048
#define NKT   (HH / BK)      // 64

#define NB_W  98304
#define NB_C  16384

__device__ __forceinline__ unsigned short f2bf(float f) {
  unsigned u = __float_as_uint(f);
  u += 0x7FFFu + ((u >> 16) & 1u);
  return (unsigned short)(u >> 16);
}
__device__ __forceinline__ float bf2f(unsigned short s) {
  return __uint_as_float(((unsigned)s) << 16);
}

__device__ __forceinline__ void gload16(const void* g, void* l) {
  void* gv = (void*)g;
  __builtin_amdgcn_global_load_lds(
      (__attribute__((address_space(1))) unsigned int*)gv,
      (__attribute__((address_space(3))) unsigned int*)l,
      16, 0, 0);
}

// --- prep: Wc row r = jg*6+g  (g<3: W_ih gate g with col half-swap;
//           g>=3: W_hh gate g-3). Also hb0 = bf16(features).
__global__ void __launch_bounds__(256)
prep(const float* __restrict__ Wih, const float* __restrict__ Whh,
     const float* __restrict__ feat,
     unsigned short* __restrict__ Wc, unsigned short* __restrict__ hb0)
{
  int bid = blockIdx.x;
  if (bid < NB_W) {
    int idx = (bid * 256 + threadIdx.x) << 2;
    int r = idx >> 12;
    int k = idx & 4095;
    int jg = r / 6;
    int g  = r - jg * 6;
    const float* src;
    if (g < 3) src = Wih + ((size_t)g * HH + jg) * HH + ((k + NI_D) & (HH - 1));
    else       src = Whh + ((size_t)(g - 3) * HH + jg) * HH + k;
    f32x4 v = *(const f32x4*)src;
    u16x4 o = { f2bf(v[0]), f2bf(v[1]), f2bf(v[2]), f2bf(v[3]) };
    *(u16x4*)(Wc + idx) = o;
  } else {
    int i = ((bid - NB_W) * 256 + threadIdx.x) << 2;
    f32x4 v = *(const f32x4*)(feat + i);
    u16x4 o = { f2bf(v[0]), f2bf(v[1]), f2bf(v[2]), f2bf(v[3]) };
    *(u16x4*)(hb0 + i) = o;
  }
}

// ---------------------------------------------------------------------------
// LDS: A buf d at d*32768 (256 rows, granules G0-3 of 64 rows);
//      B buf d at 65536 + d*24576 (192 rows, granules G0-2). Total 114688.
// Linear LDS dest; global source col pre-swizzled by ((row&7)<<4) (rule 21).
// A frags 4-7 in granules G1(wm0)/G3(wm1); frags 0-3 in G0/G2.
// ---------------------------------------------------------------------------
__device__ __forceinline__ void stageA(const char* a_base, char* lds, int ldst,
                                       int d, int kt, int g) {
  int kc = (kt < NKT) ? kt : 0;                 // dummy tail loads, race-safe
  gload16(a_base + (size_t)kc * 128 + (size_t)g * 524288,
          lds + d * 32768 + g * 8192 + ldst);
}
__device__ __forceinline__ void stageB(const char* b_base, char* lds, int ldst,
                                       int d, int kt, int g) {
  int kc = (kt < NKT) ? kt : 0;
  gload16(b_base + (size_t)kc * 128 + (size_t)g * 524288,
          lds + 65536 + d * 24576 + g * 8192 + ldst);
}

template <int MB>
__device__ __forceinline__ void mfmaQ16(f32x4 (&acc)[8][3],
                                        const bf16x8 (&af)[4][2],
                                        const bf16x8 (&bf)[2][2]) {
  __builtin_amdgcn_s_setprio(1);
#pragma unroll
  for (int ks = 0; ks < 2; ++ks)
#pragma unroll
    for (int mf = 0; mf < 4; ++mf)
#pragma unroll
      for (int nf = 0; nf < 2; ++nf)
        acc[MB + mf][nf] = __builtin_amdgcn_mfma_f32_16x16x32_bf16(
            af[mf][ks], bf[nf][ks], acc[MB + mf][nf], 0, 0, 0);
  __builtin_amdgcn_s_setprio(0);
}
template <int MB>
__device__ __forceinline__ void mfma8(f32x4 (&acc)[8][3],
                                      const bf16x8 (&af)[4][2],
                                      const bf16x8 (&b2)[2]) {
  __builtin_amdgcn_s_setprio(1);
#pragma unroll
  for (int ks = 0; ks < 2; ++ks)
#pragma unroll
    for (int mf = 0; mf < 4; ++mf)
      acc[MB + mf][2] = __builtin_amdgcn_mfma_f32_16x16x32_bf16(
          af[mf][ks], b2[ks], acc[MB + mf][2], 0, 0, 0);
  __builtin_amdgcn_s_setprio(0);
}

#define BAR   __builtin_amdgcn_s_barrier()
#define SB    __builtin_amdgcn_sched_barrier(0)
#define LGKM0 do { asm volatile("s_waitcnt lgkmcnt(0)" ::: "memory"); SB; } while (0)
#define VM6   asm volatile("s_waitcnt vmcnt(6)" ::: "memory")

// One K-tile (r7 read-ahead, 7 loads/tile). Ledger (steady, tile t):
//   ph0: A(t+1)G0,G2 -> A^1 | ph1: A(t+2)G1,G3 -> A | ph2: B(t+2)G0,G1 -> B
//   ph3: B(t+2)G2 -> B
// Gates (entry outstanding = 7): ph0-end VM6 retires A(t)G0,G2 (ph1's a03);
// ph2-end VM6 retires A(t+1)G1,G3 + B(t+1)G0,G1 (ph3's a47n/b01n) and
// B(t)G2 was retired a tile earlier (ph0's b2). Exact requirements are 7;
// 6 is strictly safe. Overwrite safety: every staged region's last LDS
// reader completed >=1 barrier before the stage issue (checked per phase).
template <int D>
__device__ __forceinline__ void kblock(char* lds, const char* a_base,
                                       const char* b_base, int ldst,
                                       int aro, int bro, int offk0, int offk1,
                                       int t1, int t2, f32x4 (&acc)[8][3],
                                       bf16x8 (&a47c)[4][2], bf16x8 (&b01c)[2][2],
                                       bf16x8 (&a47n)[4][2], bf16x8 (&b01n)[2][2]) {
  const char* LA  = lds + D * 32768 + aro;
  const char* LB  = lds + 65536 + D * 24576 + bro;
  const char* LAn = lds + (D ^ 1) * 32768 + aro;
  const char* LBn = lds + 65536 + (D ^ 1) * 24576 + bro;
  bf16x8 a03[4][2], b2[2];

  // ph0: MFMA(a47,b01) x16; read b2; stage A(t1)G0,G2 -> A^1.
  LGKM0;
  b2[0] = *(const bf16x8*)(LB + 2 * 2048 + offk0);
  b2[1] = *(const bf16x8*)(LB + 2 * 2048 + offk1);
  stageA(a_base, lds, ldst, D ^ 1, t1, 0);
  stageA(a_base, lds, ldst, D ^ 1, t1, 2);
  SB;
  mfmaQ16<4>(acc, a47c, b01c);
  VM6;
  BAR;

  // ph1: MFMA(a47,b2) x8; read a03; stage A(t2)G1,G3 -> A.
  LGKM0;
#pragma unroll
  for (int mf = 0; mf < 4; ++mf) {
    a03[mf][0] = *(const bf16x8*)(LA + mf * 2048 + offk0);
    a03[mf][1] = *(const bf16x8*)(LA + mf * 2048 + offk1);
  }
  stageA(a_base, lds, ldst, D, t2, 1);
  stageA(a_base, lds, ldst, D, t2, 3);
  SB;
  mfma8<4>(acc, a47c, b2);
  BAR;

  // ph2: MFMA(a03,b01) x16; stage B(t2)G0,G1 -> B.
  LGKM0;
  stageB(b_base, lds, ldst, D, t2, 0);
  stageB(b_base, lds, ldst, D, t2, 1);
  SB;
  mfmaQ16<0>(acc, a03, b01c);
  VM6;
  BAR;

  // ph3: MFMA(a03,b2) x8; read next tile's a47,b01 from ^1; stage B(t2)G2.
#pragma unroll
  for (int mf = 0; mf < 4; ++mf) {
    a47n[mf][0] = *(const bf16x8*)(LAn + (4 + mf) * 2048 + offk0);
    a47n[mf][1] = *(const bf16x8*)(LAn + (4 + mf) * 2048 + offk1);
  }
#pragma unroll
  for (int nf = 0; nf < 2; ++nf) {
    b01n[nf][0] = *(const bf16x8*)(LBn + nf * 2048 + offk0);
    b01n[nf][1] = *(const bf16x8*)(LBn + nf * 2048 + offk1);
  }
  stageB(b_base, lds, ldst, D, t2, 2);
  SB;
  mfma8<0>(acc, a03, b2);
  BAR;
}

// ---------------------------------------------------------------------------
// Fused GEMM(256x192) + GRU epilogue. R2=false: round 1 (h_old=feat f32,
// writes h1 bf16). R2=true: round 2 (h_old=h1 bf16, FC partial -> atomicAdd).
// ---------------------------------------------------------------------------
template <bool R2>
__global__ void __launch_bounds__(512, 2)
gemm_gru(const unsigned short* __restrict__ A,
         const unsigned short* __restrict__ B,
         const float* __restrict__ hold_f32,
         const unsigned short* __restrict__ hold_bf,
         const float* __restrict__ b_ih, const float* __restrict__ b_hh,
         unsigned short* __restrict__ h_out,
         const float* __restrict__ fcw, const float* __restrict__ fcb,
         float* __restrict__ out)
{
  __shared__ alignas(16) char lds[114688];

  int bid = blockIdx.x;
  int wg  = (bid & 7) * (GRID_GEMM / 8) + (bid >> 3);  // XCD swizzle, 2048%8==0
  int nt  = wg / MT;          // n-major: 16 consecutive wg share one W panel
  int mt  = wg % MT;
  int m0  = mt * BM;
  int n0  = nt * BN;

  int tix = threadIdx.x;
  int wv = tix >> 6;
  int l  = tix & 63;
  int wm = wv >> 2;           // 0..1: 128 C rows
  int wn = wv & 3;            // 0..3: 48 C cols

  int rloc   = wv * 8 + (l >> 3);
  int sg_col = ((l & 7) ^ (l >> 3)) << 4;
  const char* a_base = (const char*)A + (size_t)(m0 + rloc) * 8192 + sg_col;
  const char* b_base = (const char*)B + (size_t)(n0 + rloc) * 8192 + sg_col;
  int ldst = wv * 1024;

  int offk0 = ((l >> 4) << 4) ^ ((l & 7) << 4);
  int offk1 = offk0 ^ 64;
  int aro = (wm * 128 + (l & 15)) * 128;
  int bro = (wn * 48  + (l & 15)) * 128;

  f32x4 acc[8][3] = {};
  bf16x8 a47A[4][2], b01A[2][2], a47B[4][2], b01B[2][2];

  // prologue: must-land {B(0)G0-2, A(0)G1,G3} (5); in-flight, steady order:
  // {A(0)G0,G2 | A(1)G1,G3 | B(1)G0,G1 | B(1)G2} (7). vmcnt(7) retires the 5.
  stageB(b_base, lds, ldst, 0, 0, 0);
  stageB(b_base, lds, ldst, 0, 0, 1);
  stageB(b_base, lds, ldst, 0, 0, 2);
  stageA(a_base, lds, ldst, 0, 0, 1);
  stageA(a_base, lds, ldst, 0, 0, 3);
  stageA(a_base, lds, ldst, 0, 0, 0);
  stageA(a_base, lds, ldst, 0, 0, 2);
  stageA(a_base, lds, ldst, 1, 1, 1);
  stageA(a_base, lds, ldst, 1, 1, 3);
  stageB(b_base, lds, ldst, 1, 1, 0);
  stageB(b_base, lds, ldst, 1, 1, 1);
  stageB(b_base, lds, ldst, 1, 1, 2);
  asm volatile("s_waitcnt vmcnt(7)" ::: "memory");
  BAR;
  {
    const char* LA0 = lds + aro;
    const char* LB0 = lds + 65536 + bro;
#pragma unroll
    for (int mf = 0; mf < 4; ++mf) {
      a47A[mf][0] = *(const bf16x8*)(LA0 + (4 + mf) * 2048 + offk0);
      a47A[mf][1] = *(const bf16x8*)(LA0 + (4 + mf) * 2048 + offk1);
    }
#pragma unroll
    for (int nf = 0; nf < 2; ++nf) {
      b01A[nf][0] = *(const bf16x8*)(LB0 + nf * 2048 + offk0);
      b01A[nf][1] = *(const bf16x8*)(LB0 + nf * 2048 + offk1);
    }
  }

#pragma unroll 1
  for (int tt = 0; tt < NKT; tt += 2) {
    kblock<0>(lds, a_base, b_base, ldst, aro, bro, offk0, offk1,
              tt + 1, tt + 2, acc, a47A, b01A, a47B, b01B);
    kblock<1>(lds, a_base, b_base, ldst, aro, bro, offk0, offk1,
              tt + 2, tt + 3, acc, a47B, b01B, a47A, b01A);
  }
  asm volatile("s_waitcnt vmcnt(0) lgkmcnt(0)" ::: "memory");
  BAR;   // all LDS reads done block-wide before epilogue overwrite

  // ---- epilogue 1: acc -> LDS bf16 C-tile [256 rows][192 cols], stride 392B
  {
    int crow0 = wm * 128 + ((l >> 4) << 2);
    int ccol  = wn * 48 + (l & 15);
#pragma unroll
    for (int mf = 0; mf < 8; ++mf)
#pragma unroll
      for (int nf = 0; nf < 3; ++nf)
#pragma unroll
        for (int i = 0; i < 4; ++i)
          *(unsigned short*)(lds + (crow0 + mf * 16 + i) * 392 +
                             (ccol + nf * 16) * 2) = f2bf(acc[mf][nf][i]);
  }
  BAR;

  // ---- epilogue 2: GRU. thread -> batch row b = tix>>1, 16 outputs.
  {
    int b   = tix >> 1;
    int bg  = m0 + b;
    int jlb = (tix & 1) << 4;
    const char* Lrow = lds + b * 392;
    float s = 0.f;
    u16x8 h0 = {}, h1 = {};
#pragma unroll
    for (int jj = 0; jj < 16; ++jj) {
      int jl = jlb + jj;
      int jg = nt * 32 + jl;
      unsigned g01 = *(const unsigned*)(Lrow + jl * 12);
      unsigned g23 = *(const unsigned*)(Lrow + jl * 12 + 4);
      unsigned g45 = *(const unsigned*)(Lrow + jl * 12 + 8);
      float gir = bf2f((unsigned short)(g01 & 0xffff));
      float giz = bf2f((unsigned short)(g01 >> 16));
      float gin = bf2f((unsigned short)(g23 & 0xffff));
      float ghr = bf2f((unsigned short)(g23 >> 16));
      float ghz = bf2f((unsigned short)(g45 & 0xffff));
      float ghn = bf2f((unsigned short)(g45 >> 16));
      float ho;
      if constexpr (R2) ho = bf2f(hold_bf[(size_t)bg * HH + jg]);
      else              ho = hold_f32[(size_t)bg * HH + jg];
      float r = 1.f / (1.f + expf(-(gir + b_ih[jg] + ghr + b_hh[jg])));
      float z = 1.f / (1.f + expf(-(giz + b_ih[HH + jg] + ghz + b_hh[HH + jg])));
      float n = tanhf(gin + b_ih[2 * HH + jg] + r * (ghn + b_hh[2 * HH + jg]));
      float h = (1.f - z) * n + z * ho;
      if constexpr (R2) {
        s += h * fcw[jg];
      } else {
        unsigned short hv = f2bf(h);
        if (jj < 8) h0[jj] = hv; else h1[jj - 8] = hv;
      }
    }
    if constexpr (R2) {
      s += __shfl_down(s, 1);
      if ((tix & 1) == 0) {
        if (nt == 0) s += fcb[0];
        atomicAdd(&out[bg], s);
      }
    } else {
      unsigned short* hp = h_out + (size_t)bg * HH + nt * 32 + jlb;
      *(u16x8*)hp = h0;
      *(u16x8*)(hp + 8) = h1;
    }
  }
}

extern "C" void kernel_launch(void* const* d_in, const int* in_sizes, int n_in,
                              void* d_out, int out_size, void* d_ws, size_t ws_size,
                              hipStream_t stream)
{
  const float* feat = (const float*)d_in[0];
  const float* Wih  = (const float*)d_in[1];
  const float* bih  = (const float*)d_in[2];
  const float* Whh  = (const float*)d_in[3];
  const float* bhh  = (const float*)d_in[4];
  const float* fcw  = (const float*)d_in[5];
  const float* fcb  = (const float*)d_in[6];
  float* out = (float*)d_out;

  char* ws = (char*)d_ws;
  unsigned short* Wc  = (unsigned short*)ws;                   // 201326592 B
  unsigned short* hb0 = (unsigned short*)(ws + 201326592);     //  33554432 B
  unsigned short* hb1 = (unsigned short*)(ws + 234881024);     //  33554432 B
  // total: 268435456 B

  hipMemsetAsync(out, 0, (size_t)out_size * sizeof(float), stream);
  prep<<<NB_W + NB_C, 256, 0, stream>>>(Wih, Whh, feat, Wc, hb0);

  gemm_gru<false><<<GRID_GEMM, 512, 0, stream>>>(
      hb0, Wc, feat, nullptr, bih, bhh, hb1, fcw, fcb, out);
  gemm_gru<true><<<GRID_GEMM, 512, 0, stream>>>(
      hb1, Wc, nullptr, hb1, bih, bhh, nullptr, fcw, fcb, out);
}